// Round 11
// baseline (53.055 us; speedup 1.0000x reference)
//
#include <hip/hip_runtime.h>
#include <hip/hip_bf16.h>
#include <math.h>

#define CC 512
#define HH 64
#define WW 96
#define NN 16
#define HW (HH*WW)        // 6144
#define NA 9
#define NLOC 36
#define NSC 18
#define NO_PAD 64         // 54 outputs padded to 64 (4 N-tiles of 16)

typedef __attribute__((ext_vector_type(4))) float f32x4;
typedef __attribute__((ext_vector_type(8))) short s16x8;

__device__ __forceinline__ unsigned short f2bf(float f) {
    __hip_bfloat16 h = __float2bfloat16(f);
    union { __hip_bfloat16 h; unsigned short u; } cv;
    cv.h = h;
    return cv.u;
}
__device__ __forceinline__ unsigned pk2(float lo, float hi) {
    return (unsigned)f2bf(lo) | ((unsigned)f2bf(hi) << 16);
}

// ---------------------------------------------------------------------------
// Kernel 1 (fused prep): blocks 0..127 convert weights to bf16 (padded to 64
// rows, wbf[o][c]); blocks 128..343 write the anchor grid (f64, matches numpy).
// ---------------------------------------------------------------------------
__global__ void prep_kernel(const float* __restrict__ lw,
                            const float* __restrict__ sw,
                            unsigned short* __restrict__ wbf,
                            float* __restrict__ out3) {
    int b = blockIdx.x;
    if (b < 128) {
        int i = b * 256 + threadIdx.x;        // over 64*512
        int o = i >> 9, c = i & 511;
        float v = 0.0f;
        if (o < NLOC) v = lw[o * CC + c];
        else if (o < 54) v = sw[(o - NLOC) * CC + c];
        wbf[i] = f2bf(v);
    } else {
        int t = (b - 128) * 256 + threadIdx.x;   // over HW*NA
        if (t >= HW * NA) return;
        int a   = t % NA;
        int rem = t / NA;
        int h = rem / WW, w = rem % WW;
        int ri = a / 3, si = a % 3;
        const double ratios[3] = {0.5, 1.0, 2.0};
        const double scales[3] = {8.0, 16.0, 32.0};
        double ha = 16.0 * scales[si] * sqrt(ratios[ri]);
        double wa = 16.0 * scales[si] * sqrt(1.0 / ratios[ri]);
        float y1 = (float)(8.0 - ha * 0.5);
        float x1 = (float)(8.0 - wa * 0.5);
        float y2 = (float)(8.0 + ha * 0.5);
        float x2 = (float)(8.0 + wa * 0.5);
        float sy = (float)(h * 16);
        float sx = (float)(w * 16);
        float4 v = make_float4(sy + y1, sx + x1, sy + y2, sx + x2);
        *reinterpret_cast<float4*>(out3 + (size_t)t * 4) = v;
    }
}

// ---------------------------------------------------------------------------
// Kernel 2: barrier-free MFMA GEMM, M_rep=2, 4-deep circular prefetch.
// No LDS. Block = 4 independent waves over 128 consecutive positions; wave w
// owns M-tiles at pbase+w*16 and pbase+w*16+64. Round ks: issue K-step ks+3's
// 16 A-loads (issue-to-use ~3 K-steps ≈ 900+ cyc >= HBM-miss latency),
// compute K-step ks from buf[ks&3]. #pragma unroll 4 keeps all phase indices
// compile-time (rule #20: no dynamic ext-vector indexing -> no scratch).
// __launch_bounds__(256,3): 168-VGPR budget fits buf(64)+acc(32)+B(16)+addr.
// Grid = 768 = exactly 3 blocks/CU; bijective XCD swizzle (768%8==0).
// A layout: row = lane&15 (position), k = (lane>>4)*8 + j.
// B layout: col = lane&15 (output o). C/D: col = o, row = (lane>>4)*4 + reg.
// ---------------------------------------------------------------------------
__launch_bounds__(256, 3)
__global__ void rpn_mfma_kernel(const float* __restrict__ x,
                                const unsigned short* __restrict__ wbf,
                                const float* __restrict__ lb,
                                const float* __restrict__ sb,
                                float* __restrict__ out0,   // rpn_loc
                                float* __restrict__ out1,   // rpn_score
                                float* __restrict__ out2) { // rpn_fg_scores
    const int tid  = threadIdx.x;
    const int lane = tid & 63;
    const int w    = tid >> 6;        // wave id
    const int col  = lane & 15;
    const int rgrp = lane >> 4;
    const int krow = rgrp * 8;        // lane's channel slice within a K-step

    // XCD-aware bijective swizzle: 768 blocks, 8 XCDs, 96 contiguous each
    const int bid  = blockIdx.x;
    const int swz  = (bid & 7) * 96 + (bid >> 3);
    const int pbase = swz * 128;                // 128 | HW -> single n per block
    const int n     = pbase / HW;
    const int rem   = pbase % HW;
    const float* xA0 = x + (size_t)n * CC * HW + rem + w * 16 + col;  // tile m=0
    const float* xA1 = xA0 + 64;                                      // tile m=1

    f32x4 acc0[4], acc1[4];
    #pragma unroll
    for (int nt = 0; nt < 4; ++nt) {
        acc0[nt] = (f32x4){0.f, 0.f, 0.f, 0.f};
        acc1[nt] = (f32x4){0.f, 0.f, 0.f, 0.f};
    }

    float buf[4][2][8];   // [phase][tile][j] -- all indices static after unroll
    #pragma unroll
    for (int s = 0; s < 3; ++s)
        #pragma unroll
        for (int j = 0; j < 8; ++j) {
            buf[s][0][j] = xA0[(size_t)(s * 32 + krow + j) * HW];
            buf[s][1][j] = xA1[(size_t)(s * 32 + krow + j) * HW];
        }

    #pragma unroll 4
    for (int ks = 0; ks < 16; ++ks) {
        const int ph = ks & 3;
        // prefetch K-step ks+3 into the set consumed at ks-1
        if (ks < 13) {
            const int kpre = (ks + 3) * 32 + krow;
            #pragma unroll
            for (int j = 0; j < 8; ++j) {
                buf[(ks + 3) & 3][0][j] = xA0[(size_t)(kpre + j) * HW];
                buf[(ks + 3) & 3][1][j] = xA1[(size_t)(kpre + j) * HW];
            }
        }
        // B fragments: 16B contiguous, L1-hot, shared by both M-tiles
        const int kb = ks * 32;
        s16x8 bfr[4];
        #pragma unroll
        for (int nt = 0; nt < 4; ++nt)
            bfr[nt] = *reinterpret_cast<const s16x8*>(
                wbf + (size_t)(nt * 16 + col) * CC + kb + krow);
        // pack current phase to bf16 fragments
        union { unsigned u[4]; s16x8 v; } fa0, fa1;
        #pragma unroll
        for (int j = 0; j < 4; ++j) {
            fa0.u[j] = pk2(buf[ph][0][2 * j], buf[ph][0][2 * j + 1]);
            fa1.u[j] = pk2(buf[ph][1][2 * j], buf[ph][1][2 * j + 1]);
        }

        #pragma unroll
        for (int nt = 0; nt < 4; ++nt)
            acc0[nt] = __builtin_amdgcn_mfma_f32_16x16x32_bf16(fa0.v, bfr[nt], acc0[nt], 0, 0, 0);
        #pragma unroll
        for (int nt = 0; nt < 4; ++nt)
            acc1[nt] = __builtin_amdgcn_mfma_f32_16x16x32_bf16(fa1.v, bfr[nt], acc1[nt], 0, 0, 0);
    }

    // ---- epilogue: bias + stores + fg softmax (score pairs in lanes l, l^1) ----
    #pragma unroll
    for (int m = 0; m < 2; ++m) {
        #pragma unroll
        for (int nt = 0; nt < 4; ++nt) {
            int o = nt * 16 + col;
            float bias = (o < NLOC) ? lb[o] : ((o < 54) ? sb[o - NLOC] : 0.0f);
            #pragma unroll
            for (int r = 0; r < 4; ++r) {
                float val  = (m == 0 ? acc0[nt][r] : acc1[nt][r]) + bias;
                float part = __shfl_xor(val, 1);
                int p = pbase + w * 16 + m * 64 + rgrp * 4 + r;
                if (o < NLOC) {
                    out0[(size_t)p * NLOC + o] = val;
                } else if (o < 54) {
                    int os = o - NLOC;
                    out1[(size_t)p * NSC + os] = val;
                    if ((os & 1) == 0)
                        out2[(size_t)p * NA + (os >> 1)] = 1.0f / (1.0f + __expf(val - part));
                }
            }
        }
    }
}

extern "C" void kernel_launch(void* const* d_in, const int* in_sizes, int n_in,
                              void* d_out, int out_size, void* d_ws, size_t ws_size,
                              hipStream_t stream) {
    const float* x  = (const float*)d_in[0];
    const float* lw = (const float*)d_in[1];
    const float* lb = (const float*)d_in[2];
    const float* sw = (const float*)d_in[3];
    const float* sb = (const float*)d_in[4];

    float* out0 = (float*)d_out;                          // (16, 55296, 4)
    float* out1 = out0 + (size_t)NN * HW * NLOC;          // (16, 64, 96, 18)
    float* out2 = out1 + (size_t)NN * HW * NSC;           // (16, 55296)
    float* out3 = out2 + (size_t)NN * HW * NA;            // (55296, 4)

    unsigned short* wbf = (unsigned short*)d_ws;          // 64*512*2 = 64 KB

    prep_kernel<<<344, 256, 0, stream>>>(lw, sw, wbf, out3);

    int grid_m = NN * HW / 128;                           // 768
    rpn_mfma_kernel<<<grid_m, 256, 0, stream>>>(x, wbf, lb, sb, out0, out1, out2);
}

// Round 12
// 51.828 us; speedup vs baseline: 1.0237x; 1.0237x over previous
//
#include <hip/hip_runtime.h>
#include <hip/hip_bf16.h>
#include <math.h>

#define CC 512
#define HH 64
#define WW 96
#define NN 16
#define HW (HH*WW)        // 6144
#define NA 9
#define NLOC 36
#define NSC 18
#define NO_PAD 64         // 54 outputs padded to 64 (4 N-tiles of 16)

typedef __attribute__((ext_vector_type(4))) float f32x4;
typedef __attribute__((ext_vector_type(2))) float f32x2;
typedef __attribute__((ext_vector_type(8))) short s16x8;

__device__ __forceinline__ unsigned short f2bf(float f) {
    __hip_bfloat16 h = __float2bfloat16(f);
    union { __hip_bfloat16 h; unsigned short u; } cv;
    cv.h = h;
    return cv.u;
}
__device__ __forceinline__ unsigned pk2(float lo, float hi) {
    return (unsigned)f2bf(lo) | ((unsigned)f2bf(hi) << 16);
}

// ---------------------------------------------------------------------------
// Kernel 1: weights -> bf16, padded to 64 rows. wbf[o][c], c contiguous.
// (anchors moved into the main kernel's tail)
// ---------------------------------------------------------------------------
__global__ void prep_w_kernel(const float* __restrict__ lw,
                              const float* __restrict__ sw,
                              unsigned short* __restrict__ wbf) {
    int i = blockIdx.x * 256 + threadIdx.x;   // over 64*512
    if (i >= NO_PAD * CC) return;
    int o = i >> 9, c = i & 511;
    float v = 0.0f;
    if (o < NLOC) v = lw[o * CC + c];
    else if (o < 54) v = sw[(o - NLOC) * CC + c];
    wbf[i] = f2bf(v);
}

// ---------------------------------------------------------------------------
// Kernel 2: barrier-free MFMA GEMM, M_rep=2 via EVEN/ODD position split.
// Block = 4 independent waves over 128 consecutive positions; wave w owns a
// 32-position window [pbase+w*32, +32): tile0 = even positions, tile1 = odd.
// A-load = float2 per lane -> each instruction covers 4 FULL 128B lines
// (512B/instr, no half-line requests; halves VMEM instr count vs r10).
// Ping-pong depth-2 prefetch (proven r10); no LDS, no barriers.
// Grid = 768 = 3 blocks/CU; bijective XCD swizzle (768%8==0) -> each XCD
// streams a contiguous ~25MB slab of x.
// A layout: row = lane&15 (pos-in-tile), k = (lane>>4)*8 + j.
// B layout: col = lane&15 (output o). C/D: col = o, row = (lane>>4)*4 + reg;
// row r of tile m -> global position pbase + w*32 + 2*row + m.
// Tail: each block writes its 72-float4 slice of the anchor grid (768*72 =
// 55296 anchors exactly).
// ---------------------------------------------------------------------------
__launch_bounds__(256, 3)
__global__ void rpn_mfma_kernel(const float* __restrict__ x,
                                const unsigned short* __restrict__ wbf,
                                const float* __restrict__ lb,
                                const float* __restrict__ sb,
                                float* __restrict__ out0,   // rpn_loc
                                float* __restrict__ out1,   // rpn_score
                                float* __restrict__ out2,   // rpn_fg_scores
                                float* __restrict__ out3) { // anchors
    const int tid  = threadIdx.x;
    const int lane = tid & 63;
    const int w    = tid >> 6;        // wave id
    const int col  = lane & 15;
    const int rgrp = lane >> 4;
    const int krow = rgrp * 8;        // lane's channel slice within a K-step

    // XCD-aware bijective swizzle: 768 blocks, 8 XCDs, 96 contiguous each
    const int bid  = blockIdx.x;
    const int swz  = (bid & 7) * 96 + (bid >> 3);
    const int pbase = swz * 128;                // 128 | HW -> single n per block
    const int n     = pbase / HW;
    const int rem   = pbase % HW;
    // lane's float2 base: two adjacent positions (even=tile0, odd=tile1)
    const float* xA = x + (size_t)n * CC * HW + rem + w * 32 + 2 * col;

    f32x4 acc0[4], acc1[4];
    #pragma unroll
    for (int nt = 0; nt < 4; ++nt) {
        acc0[nt] = (f32x4){0.f, 0.f, 0.f, 0.f};
        acc1[nt] = (f32x4){0.f, 0.f, 0.f, 0.f};
    }

    f32x2 a[8], p[8];
    #pragma unroll
    for (int j = 0; j < 8; ++j)
        a[j] = *reinterpret_cast<const f32x2*>(xA + (size_t)(krow + j) * HW);

    #pragma unroll 2
    for (int ks = 0; ks < 16; ++ks) {
        const int kb = ks * 32;
        // prefetch next K-step (8 full-line float2 loads in flight)
        if (ks < 15) {
            #pragma unroll
            for (int j = 0; j < 8; ++j)
                p[j] = *reinterpret_cast<const f32x2*>(
                    xA + (size_t)(kb + 32 + krow + j) * HW);
        }
        // B fragments: 16B contiguous, L1-hot, shared by both M-tiles
        s16x8 bfr[4];
        #pragma unroll
        for (int nt = 0; nt < 4; ++nt)
            bfr[nt] = *reinterpret_cast<const s16x8*>(
                wbf + (size_t)(nt * 16 + col) * CC + kb + krow);
        // pack A fragments: tile0 = .x (even pos), tile1 = .y (odd pos)
        union { unsigned u[4]; s16x8 v; } fa0, fa1;
        #pragma unroll
        for (int j = 0; j < 4; ++j) {
            fa0.u[j] = pk2(a[2 * j].x, a[2 * j + 1].x);
            fa1.u[j] = pk2(a[2 * j].y, a[2 * j + 1].y);
        }

        #pragma unroll
        for (int nt = 0; nt < 4; ++nt)
            acc0[nt] = __builtin_amdgcn_mfma_f32_16x16x32_bf16(fa0.v, bfr[nt], acc0[nt], 0, 0, 0);
        #pragma unroll
        for (int nt = 0; nt < 4; ++nt)
            acc1[nt] = __builtin_amdgcn_mfma_f32_16x16x32_bf16(fa1.v, bfr[nt], acc1[nt], 0, 0, 0);

        #pragma unroll
        for (int j = 0; j < 8; ++j) a[j] = p[j];
    }

    // ---- epilogue: bias + stores + fg softmax (score pairs in lanes l, l^1) ----
    #pragma unroll
    for (int m = 0; m < 2; ++m) {
        #pragma unroll
        for (int nt = 0; nt < 4; ++nt) {
            int o = nt * 16 + col;
            float bias = (o < NLOC) ? lb[o] : ((o < 54) ? sb[o - NLOC] : 0.0f);
            #pragma unroll
            for (int r = 0; r < 4; ++r) {
                float val  = (m == 0 ? acc0[nt][r] : acc1[nt][r]) + bias;
                float part = __shfl_xor(val, 1);
                int pgl = pbase + w * 32 + 2 * (rgrp * 4 + r) + m;   // even/odd
                if (o < NLOC) {
                    out0[(size_t)pgl * NLOC + o] = val;
                } else if (o < 54) {
                    int os = o - NLOC;
                    out1[(size_t)pgl * NSC + os] = val;
                    if ((os & 1) == 0)
                        out2[(size_t)pgl * NA + (os >> 1)] = 1.0f / (1.0f + __expf(val - part));
                }
            }
        }
    }

    // ---- tail: this block's 72-anchor slice (768*72 = 55296 exactly) ----
    if (tid < 72) {
        int t = bid * 72 + tid;
        int a9   = t % NA;
        int rem2 = t / NA;
        int h = rem2 / WW, ww2 = rem2 % WW;
        int ri = a9 / 3, si = a9 % 3;
        const double ratios[3] = {0.5, 1.0, 2.0};
        const double scales[3] = {8.0, 16.0, 32.0};
        double ha = 16.0 * scales[si] * sqrt(ratios[ri]);
        double wa = 16.0 * scales[si] * sqrt(1.0 / ratios[ri]);
        float y1 = (float)(8.0 - ha * 0.5);
        float x1 = (float)(8.0 - wa * 0.5);
        float y2 = (float)(8.0 + ha * 0.5);
        float x2 = (float)(8.0 + wa * 0.5);
        float sy = (float)(h * 16);
        float sx = (float)(ww2 * 16);
        float4 v = make_float4(sy + y1, sx + x1, sy + y2, sx + x2);
        *reinterpret_cast<float4*>(out3 + (size_t)t * 4) = v;
    }
}

extern "C" void kernel_launch(void* const* d_in, const int* in_sizes, int n_in,
                              void* d_out, int out_size, void* d_ws, size_t ws_size,
                              hipStream_t stream) {
    const float* x  = (const float*)d_in[0];
    const float* lw = (const float*)d_in[1];
    const float* lb = (const float*)d_in[2];
    const float* sw = (const float*)d_in[3];
    const float* sb = (const float*)d_in[4];

    float* out0 = (float*)d_out;                          // (16, 55296, 4)
    float* out1 = out0 + (size_t)NN * HW * NLOC;          // (16, 64, 96, 18)
    float* out2 = out1 + (size_t)NN * HW * NSC;           // (16, 55296)
    float* out3 = out2 + (size_t)NN * HW * NA;            // (55296, 4)

    unsigned short* wbf = (unsigned short*)d_ws;          // 64*512*2 = 64 KB

    int grid_w = (NO_PAD * CC + 255) / 256;               // 128
    prep_w_kernel<<<grid_w, 256, 0, stream>>>(lw, sw, wbf);

    int grid_m = NN * HW / 128;                           // 768
    rpn_mfma_kernel<<<grid_m, 256, 0, stream>>>(x, wbf, lb, sb, out0, out1, out2, out3);
}

// Round 13
// 50.797 us; speedup vs baseline: 1.0444x; 1.0203x over previous
//
#include <hip/hip_runtime.h>
#include <hip/hip_bf16.h>
#include <math.h>

#define CC 512
#define HH 64
#define WW 96
#define NN 16
#define HW (HH*WW)        // 6144
#define NA 9
#define NLOC 36
#define NSC 18
#define NO_PAD 64         // 54 outputs padded to 64 (4 N-tiles of 16)

typedef __attribute__((ext_vector_type(4))) float f32x4;
typedef __attribute__((ext_vector_type(2))) float f32x2;
typedef __attribute__((ext_vector_type(8))) short s16x8;

__device__ __forceinline__ unsigned short f2bf(float f) {
    __hip_bfloat16 h = __float2bfloat16(f);
    union { __hip_bfloat16 h; unsigned short u; } cv;
    cv.h = h;
    return cv.u;
}
__device__ __forceinline__ unsigned pk2(float lo, float hi) {
    return (unsigned)f2bf(lo) | ((unsigned)f2bf(hi) << 16);
}

// ---------------------------------------------------------------------------
// Kernel 1: weights -> bf16, padded to 64 rows. wbf[o][c], c contiguous.
// ---------------------------------------------------------------------------
__global__ void prep_w_kernel(const float* __restrict__ lw,
                              const float* __restrict__ sw,
                              unsigned short* __restrict__ wbf) {
    int i = blockIdx.x * 256 + threadIdx.x;   // over 64*512
    if (i >= NO_PAD * CC) return;
    int o = i >> 9, c = i & 511;
    float v = 0.0f;
    if (o < NLOC) v = lw[o * CC + c];
    else if (o < 54) v = sw[(o - NLOC) * CC + c];
    wbf[i] = f2bf(v);
}

// ---------------------------------------------------------------------------
// Kernel 2: barrier-free MFMA GEMM, M_rep=2 (even/odd positions), with BOTH
// A and B double-buffered in registers. The r9-r12 bug: B was loaded and
// consumed in the same K-step, so the MFMA's wait drained vmcnt to 0 every
// step (in-order counter), killing the A-prefetch. Now iteration k computes
// from set A while issuing k+1 into set B -> compiler emits counted vmcnt
// (12 loads stay in flight), no drains, latency fully hidden.
// Block = 4 independent waves x 32-pos windows; A-load = float2 per lane
// (full 128B lines). Grid = 768 = 3 blocks/CU; bijective XCD swizzle.
// A layout: row = lane&15 (pos pair), k = (lane>>4)*8 + j.
// B layout: col = lane&15 (output o). C/D: col = o, row = (lane>>4)*4 + reg;
// row r of tile m -> global position pbase + w*32 + 2*row + m.
// ---------------------------------------------------------------------------
__launch_bounds__(256, 3)
__global__ void rpn_mfma_kernel(const float* __restrict__ x,
                                const unsigned short* __restrict__ wbf,
                                const float* __restrict__ lb,
                                const float* __restrict__ sb,
                                float* __restrict__ out0,   // rpn_loc
                                float* __restrict__ out1,   // rpn_score
                                float* __restrict__ out2,   // rpn_fg_scores
                                float* __restrict__ out3) { // anchors
    const int tid  = threadIdx.x;
    const int lane = tid & 63;
    const int w    = tid >> 6;        // wave id
    const int col  = lane & 15;
    const int rgrp = lane >> 4;
    const int krow = rgrp * 8;        // lane's channel slice within a K-step

    // XCD-aware bijective swizzle: 768 blocks, 8 XCDs, 96 contiguous each
    const int bid  = blockIdx.x;
    const int swz  = (bid & 7) * 96 + (bid >> 3);
    const int pbase = swz * 128;                // 128 | HW -> single n per block
    const int n     = pbase / HW;
    const int rem   = pbase % HW;
    const float* xA = x + (size_t)n * CC * HW + rem + w * 32 + 2 * col;
    const unsigned short* wB = wbf + (size_t)col * CC + krow;   // + nt*16*CC + kb

    f32x4 acc0[4], acc1[4];
    #pragma unroll
    for (int nt = 0; nt < 4; ++nt) {
        acc0[nt] = (f32x4){0.f, 0.f, 0.f, 0.f};
        acc1[nt] = (f32x4){0.f, 0.f, 0.f, 0.f};
    }

    f32x2 aA[8], aB[8];
    s16x8 bA[4], bB[4];

    // ---- preload K-step 0 into set A ----
    #pragma unroll
    for (int j = 0; j < 8; ++j)
        aA[j] = *reinterpret_cast<const f32x2*>(xA + (size_t)(krow + j) * HW);
    #pragma unroll
    for (int nt = 0; nt < 4; ++nt)
        bA[nt] = *reinterpret_cast<const s16x8*>(wB + (size_t)nt * 16 * CC);

    #pragma unroll 1
    for (int ks = 0; ks < 16; ks += 2) {
        const int kb1 = (ks + 1) * 32;
        const int kb2 = (ks + 2) * 32;

        // issue K-step ks+1 into set B (ks+1 <= 15 always)
        #pragma unroll
        for (int j = 0; j < 8; ++j)
            aB[j] = *reinterpret_cast<const f32x2*>(
                xA + (size_t)(kb1 + krow + j) * HW);
        #pragma unroll
        for (int nt = 0; nt < 4; ++nt)
            bB[nt] = *reinterpret_cast<const s16x8*>(
                wB + (size_t)nt * 16 * CC + kb1);

        // compute K-step ks from set A (waits only on set-A regs -> counted vmcnt)
        {
            union { unsigned u[4]; s16x8 v; } fa0, fa1;
            #pragma unroll
            for (int j = 0; j < 4; ++j) {
                fa0.u[j] = pk2(aA[2 * j].x, aA[2 * j + 1].x);
                fa1.u[j] = pk2(aA[2 * j].y, aA[2 * j + 1].y);
            }
            #pragma unroll
            for (int nt = 0; nt < 4; ++nt)
                acc0[nt] = __builtin_amdgcn_mfma_f32_16x16x32_bf16(fa0.v, bA[nt], acc0[nt], 0, 0, 0);
            #pragma unroll
            for (int nt = 0; nt < 4; ++nt)
                acc1[nt] = __builtin_amdgcn_mfma_f32_16x16x32_bf16(fa1.v, bA[nt], acc1[nt], 0, 0, 0);
        }

        // issue K-step ks+2 into set A
        if (ks < 14) {
            #pragma unroll
            for (int j = 0; j < 8; ++j)
                aA[j] = *reinterpret_cast<const f32x2*>(
                    xA + (size_t)(kb2 + krow + j) * HW);
            #pragma unroll
            for (int nt = 0; nt < 4; ++nt)
                bA[nt] = *reinterpret_cast<const s16x8*>(
                    wB + (size_t)nt * 16 * CC + kb2);
        }

        // compute K-step ks+1 from set B
        {
            union { unsigned u[4]; s16x8 v; } fa0, fa1;
            #pragma unroll
            for (int j = 0; j < 4; ++j) {
                fa0.u[j] = pk2(aB[2 * j].x, aB[2 * j + 1].x);
                fa1.u[j] = pk2(aB[2 * j].y, aB[2 * j + 1].y);
            }
            #pragma unroll
            for (int nt = 0; nt < 4; ++nt)
                acc0[nt] = __builtin_amdgcn_mfma_f32_16x16x32_bf16(fa0.v, bB[nt], acc0[nt], 0, 0, 0);
            #pragma unroll
            for (int nt = 0; nt < 4; ++nt)
                acc1[nt] = __builtin_amdgcn_mfma_f32_16x16x32_bf16(fa1.v, bB[nt], acc1[nt], 0, 0, 0);
        }
    }

    // ---- epilogue: bias + stores + fg softmax (score pairs in lanes l, l^1) ----
    #pragma unroll
    for (int m = 0; m < 2; ++m) {
        #pragma unroll
        for (int nt = 0; nt < 4; ++nt) {
            int o = nt * 16 + col;
            float bias = (o < NLOC) ? lb[o] : ((o < 54) ? sb[o - NLOC] : 0.0f);
            #pragma unroll
            for (int r = 0; r < 4; ++r) {
                float val  = (m == 0 ? acc0[nt][r] : acc1[nt][r]) + bias;
                float part = __shfl_xor(val, 1);
                int pgl = pbase + w * 32 + 2 * (rgrp * 4 + r) + m;   // even/odd
                if (o < NLOC) {
                    out0[(size_t)pgl * NLOC + o] = val;
                } else if (o < 54) {
                    int os = o - NLOC;
                    out1[(size_t)pgl * NSC + os] = val;
                    if ((os & 1) == 0)
                        out2[(size_t)pgl * NA + (os >> 1)] = 1.0f / (1.0f + __expf(val - part));
                }
            }
        }
    }

    // ---- tail: this block's 72-anchor slice (768*72 = 55296 exactly) ----
    if (tid < 72) {
        int t = bid * 72 + tid;
        int a9   = t % NA;
        int rem2 = t / NA;
        int h = rem2 / WW, ww2 = rem2 % WW;
        int ri = a9 / 3, si = a9 % 3;
        const double ratios[3] = {0.5, 1.0, 2.0};
        const double scales[3] = {8.0, 16.0, 32.0};
        double ha = 16.0 * scales[si] * sqrt(ratios[ri]);
        double wa = 16.0 * scales[si] * sqrt(1.0 / ratios[ri]);
        float y1 = (float)(8.0 - ha * 0.5);
        float x1 = (float)(8.0 - wa * 0.5);
        float y2 = (float)(8.0 + ha * 0.5);
        float x2 = (float)(8.0 + wa * 0.5);
        float sy = (float)(h * 16);
        float sx = (float)(ww2 * 16);
        float4 v = make_float4(sy + y1, sx + x1, sy + y2, sx + x2);
        *reinterpret_cast<float4*>(out3 + (size_t)t * 4) = v;
    }
}

extern "C" void kernel_launch(void* const* d_in, const int* in_sizes, int n_in,
                              void* d_out, int out_size, void* d_ws, size_t ws_size,
                              hipStream_t stream) {
    const float* x  = (const float*)d_in[0];
    const float* lw = (const float*)d_in[1];
    const float* lb = (const float*)d_in[2];
    const float* sw = (const float*)d_in[3];
    const float* sb = (const float*)d_in[4];

    float* out0 = (float*)d_out;                          // (16, 55296, 4)
    float* out1 = out0 + (size_t)NN * HW * NLOC;          // (16, 64, 96, 18)
    float* out2 = out1 + (size_t)NN * HW * NSC;           // (16, 55296)
    float* out3 = out2 + (size_t)NN * HW * NA;            // (55296, 4)

    unsigned short* wbf = (unsigned short*)d_ws;          // 64*512*2 = 64 KB

    int grid_w = (NO_PAD * CC + 255) / 256;               // 128
    prep_w_kernel<<<grid_w, 256, 0, stream>>>(lw, sw, wbf);

    int grid_m = NN * HW / 128;                           // 768
    rpn_mfma_kernel<<<grid_m, 256, 0, stream>>>(x, wbf, lb, sb, out0, out1, out2, out3);
}